// Round 1
// baseline (1831.944 us; speedup 1.0000x reference)
//
#include <hip/hip_runtime.h>
#include <math.h>

#define ND  256    // num_data (steps)
#define SEQ 2048
#define NI  256
#define NH  1024
#define NO  256

#define RB   64                 // recur blocks (all co-resident: 1 block/CU)
#define RT   1024               // recur threads (16 waves)
#define HPB  16                 // hidden units per block (NH / RB)
#define NHP  (NH + 1)           // padded LDS row (break 16-way write conflicts)

#define XTB  32                 // t-tile for xproj
#define OTB  8                  // t-tile for outproj

typedef unsigned long long u64;

// relaxed agent-scope atomics: compile to sc0|sc1 ops that bypass/write-through
// L1+L2 to the device coherence point (IF). The 8-byte payload packs
// {tag:32 | float_bits:32}, so tag+value are atomically consistent — no fence,
// no waitcnt drain, no separate barrier variable needed anywhere.
#define AL64(p)    __hip_atomic_load((p), __ATOMIC_RELAXED, __HIP_MEMORY_SCOPE_AGENT)
#define AS64(p,v)  __hip_atomic_store((p), (v), __ATOMIC_RELAXED, __HIP_MEMORY_SCOPE_AGENT)

// ---------------- input projections, t-tiled: X[t][h] = b[h] + x[t,2047,:]@W --
__global__ void xproj(const float* __restrict__ x,
                      const float* __restrict__ Win1, const float* __restrict__ b1,
                      const float* __restrict__ Win2, const float* __restrict__ b2,
                      float* __restrict__ X1, float* __restrict__ X2) {
    const int   layer = blockIdx.z;
    const int   t0    = blockIdx.y * XTB;
    const int   h     = blockIdx.x * 256 + threadIdx.x;
    const float* W = layer ? Win2 : Win1;
    const float* b = layer ? b2   : b1;
    float*       X = layer ? X2   : X1;

    __shared__ float lx[XTB][NI];          // 32 KB: last seq row for 32 t's
    for (int idx = threadIdx.x; idx < XTB * NI; idx += 256) {
        int r = idx >> 8, c = idx & (NI - 1);
        lx[r][c] = x[(size_t)(t0 + r) * SEQ * NI + (size_t)(SEQ - 1) * NI + c];
    }
    __syncthreads();

    float acc[XTB];
    float bias = b[h];
    #pragma unroll
    for (int r = 0; r < XTB; ++r) acc[r] = bias;

    for (int i = 0; i < NI; ++i) {
        float wv = W[i * NH + h];          // coalesced over h, L1/L2-cached
        #pragma unroll
        for (int r = 0; r < XTB; ++r) acc[r] += lx[r][i] * wv;
    }
    #pragma unroll
    for (int r = 0; r < XTB; ++r) X[(t0 + r) * NH + h] = acc[r];
}

// ---------------- sequential recurrence: 64 blocks, weights LDS-resident -----
// Synchronization: generation-tagged data polling. State vector element h at
// step t lives in ping-pong buffer (t&1) as {tag=t, value}. Consumers poll
// their own element until the tag matches; producers just store (write-through
// to IF). No grid barrier, no vmcnt drain, no atomic counter.
//
// Safety: a block publishes tag t+1 only after its block-wide barrier, which
// requires every wave's step-t poll to have hit — so by induction no element
// anywhere can carry tag t+2 while any thread still polls for t (no overshoot,
// 2-deep ping-pong suffices). LDS staging is double-buffered, so the single
// per-step __syncthreads also protects sz reuse (overwrite of sz[p] happens
// 2 steps later, provably after all reads of sz[p]).
__launch_bounds__(RT, 1)
__global__ void recur(const float* __restrict__ Wr1, const float* __restrict__ Wr2,
                      const float* __restrict__ X1,  const float* __restrict__ X2,
                      u64* Z12, u64* Z2, float* Z1hist) {
    __shared__ float lW1[HPB][NHP];        // 64 KB (+pad)
    __shared__ float lW2[HPB][NHP];        // 64 KB (+pad)
    __shared__ float sz [2][NH];           // 8 KB  z12 staging (double-buffered)
    __shared__ float sz2[2][NH];           // 8 KB  z2 staging  (double-buffered)

    const int tid = threadIdx.x;
    const int h0  = blockIdx.x * HPB;

    // one-time weight residency: consecutive tid -> consecutive h (64B chunks)
    for (int idx = tid; idx < HPB * NH; idx += RT) {
        int hw = idx & (HPB - 1);
        int k  = idx >> 4;                 // HPB == 16
        lW1[hw][k] = Wr1[(size_t)k * NH + h0 + hw];
        lW2[hw][k] = Wr2[(size_t)k * NH + h0 + hw];
    }
    __syncthreads();

    const int w = tid >> 6;                // wave 0..15 <-> hidden unit
    const int l = tid & 63;
    const int h = h0 + w;

    float z2h = 0.0f;                      // lane-0-owned z2[h] register state

    for (int t = 0; t < ND; ++t) {
        const bool even = (t & 1) == 0;
        const int  q    = t >> 1;

        // issue cached X loads early — independent of the polls below
        float xv1 = X1[t * NH + h];
        float xv2 = even ? X2[t * NH + h] : 0.0f;

        // poll own element of step-t state (tag == t), stage to LDS
        const u64* p1 = Z12 + (t & 1) * NH + tid;
        u64 v1 = AL64(p1);
        u64 v2 = 0;
        const u64* p2 = Z2 + (q & 1) * NH + tid;
        if (even) v2 = AL64(p2);           // overlap both poll streams
        while ((unsigned)(v1 >> 32) != (unsigned)t) v1 = AL64(p1);
        sz[t & 1][tid] = __uint_as_float((unsigned)v1);
        if (even) {
            while ((unsigned)(v2 >> 32) != (unsigned)q) v2 = AL64(p2);
            sz2[q & 1][tid] = __uint_as_float((unsigned)v2);
        }
        __syncthreads();                   // the ONLY barrier per step

        float r1 = 0.0f, r2 = 0.0f;
        #pragma unroll
        for (int j = 0; j < 16; ++j) {
            int k = l + 64 * j;            // conflict-free LDS
            r1 += sz[t & 1][k] * lW1[w][k];
        }
        if (even) {
            #pragma unroll
            for (int j = 0; j < 16; ++j) {
                int k = l + 64 * j;
                r2 += sz2[q & 1][k] * lW2[w][k];
            }
        }
        #pragma unroll
        for (int off = 32; off; off >>= 1) r1 += __shfl_xor(r1, off, 64);
        if (even) {
            #pragma unroll
            for (int off = 32; off; off >>= 1) r2 += __shfl_xor(r2, off, 64);
        }

        if (l == 0) {
            float z1n = tanhf(xv1 + r1);
            if (even) z2h = tanhf(xv2 + r2);
            Z1hist[t * NH + h] = z1n;      // cached (read only after kernel end)
            u64 o1 = ((u64)(unsigned)(t + 1) << 32) | (u64)__float_as_uint(z1n + z2h);
            AS64(Z12 + ((t + 1) & 1) * NH + h, o1);
            if (even) {
                u64 o2 = ((u64)(unsigned)(q + 1) << 32) | (u64)__float_as_uint(z2h);
                AS64(Z2 + ((q + 1) & 1) * NH + h, o2);
            }
        }
        // no trailing barrier: next iteration's poll fills the OTHER sz buffer
    }
}

// ---------------- output projection, t-tiled: out[t] = tanh(z1[t]@Wout + b) --
__global__ void outproj(const float* __restrict__ Z1hist,
                        const float* __restrict__ Wout,
                        const float* __restrict__ bout,
                        float* __restrict__ out) {
    const int t0 = blockIdx.x * OTB;
    const int o  = threadIdx.x;

    __shared__ float lz[OTB][NH];          // 32 KB
    for (int idx = threadIdx.x; idx < OTB * NH; idx += 256) {
        int r = idx >> 10, c = idx & (NH - 1);
        lz[r][c] = Z1hist[(t0 + r) * NH + c];
    }
    __syncthreads();

    float acc[OTB];
    float bias = bout[o];
    #pragma unroll
    for (int r = 0; r < OTB; ++r) acc[r] = bias;

    for (int hh = 0; hh < NH; ++hh) {
        float wv = Wout[hh * NO + o];      // coalesced over o
        #pragma unroll
        for (int r = 0; r < OTB; ++r) acc[r] += lz[r][hh] * wv;
    }
    #pragma unroll
    for (int r = 0; r < OTB; ++r) out[(t0 + r) * NO + o] = tanhf(acc[r]);
}

extern "C" void kernel_launch(void* const* d_in, const int* in_sizes, int n_in,
                              void* d_out, int out_size, void* d_ws, size_t ws_size,
                              hipStream_t stream) {
    const float* x     = (const float*)d_in[0];
    const float* Win1  = (const float*)d_in[1];
    const float* b1    = (const float*)d_in[2];
    const float* Wr1   = (const float*)d_in[3];
    const float* Win2  = (const float*)d_in[4];
    const float* b2    = (const float*)d_in[5];
    const float* Wr2   = (const float*)d_in[6];
    const float* Wout  = (const float*)d_in[7];
    const float* bout  = (const float*)d_in[8];
    float* out = (float*)d_out;

    // workspace layout
    u64*   Z12 = (u64*)d_ws;                // 2*NH u64  ping-pong {tag|z1+z2}
    u64*   Z2  = Z12 + 2 * NH;              // 2*NH u64  ping-pong {tag|z2}
    float* Z1h = (float*)(Z2 + 2 * NH);     // ND*NH
    float* X1  = Z1h + ND * NH;             // ND*NH
    float* X2  = X1 + ND * NH;              // ND*NH

    // zero initial state: value 0.0f with tag 0 == "state before step 0"
    hipMemsetAsync(Z12, 0, 4 * NH * sizeof(u64), stream);

    dim3 xg(NH / 256, ND / XTB, 2);
    xproj<<<xg, 256, 0, stream>>>(x, Win1, b1, Win2, b2, X1, X2);

    recur<<<RB, RT, 0, stream>>>(Wr1, Wr2, X1, X2, Z12, Z2, Z1h);

    outproj<<<ND / OTB, NO, 0, stream>>>(Z1h, Wout, bout, out);
}

// Round 2
// 1586.175 us; speedup vs baseline: 1.1549x; 1.1549x over previous
//
#include <hip/hip_runtime.h>
#include <math.h>

#define ND  256    // num_data (steps)
#define SEQ 2048
#define NI  256
#define NH  1024
#define NO  256

#define RB   64                 // recur blocks (all co-resident: 1 block/CU)
#define RT   1024               // recur threads (16 waves)
#define HPB  16                 // hidden units per block (NH / RB)
#define NHP  (NH + 1)           // padded LDS row (break 16-way write conflicts)

#define XTB  32                 // t-tile for xproj
#define OTB  8                  // t-tile for outproj

// relaxed agent-scope atomics: compile to sc0|sc1 ops that bypass/write-through
// L1+L2 to the device coherence point (IF) — no buffer_wbl2/buffer_inv needed.
#define ALF(p)   __hip_atomic_load((p), __ATOMIC_RELAXED, __HIP_MEMORY_SCOPE_AGENT)
#define ASF(p,v) __hip_atomic_store((p), (v), __ATOMIC_RELAXED, __HIP_MEMORY_SCOPE_AGENT)

// ---------------- input projections, t-tiled: X[t][h] = b[h] + x[t,2047,:]@W --
__global__ void xproj(const float* __restrict__ x,
                      const float* __restrict__ Win1, const float* __restrict__ b1,
                      const float* __restrict__ Win2, const float* __restrict__ b2,
                      float* __restrict__ X1, float* __restrict__ X2) {
    const int   layer = blockIdx.z;
    const int   t0    = blockIdx.y * XTB;
    const int   h     = blockIdx.x * 256 + threadIdx.x;
    const float* W = layer ? Win2 : Win1;
    const float* b = layer ? b2   : b1;
    float*       X = layer ? X2   : X1;

    __shared__ float lx[XTB][NI];          // 32 KB: last seq row for 32 t's
    for (int idx = threadIdx.x; idx < XTB * NI; idx += 256) {
        int r = idx >> 8, c = idx & (NI - 1);
        lx[r][c] = x[(size_t)(t0 + r) * SEQ * NI + (size_t)(SEQ - 1) * NI + c];
    }
    __syncthreads();

    float acc[XTB];
    float bias = b[h];
    #pragma unroll
    for (int r = 0; r < XTB; ++r) acc[r] = bias;

    for (int i = 0; i < NI; ++i) {
        float wv = W[i * NH + h];          // coalesced over h, L1/L2-cached
        #pragma unroll
        for (int r = 0; r < XTB; ++r) acc[r] += lx[r][i] * wv;
    }
    #pragma unroll
    for (int r = 0; r < XTB; ++r) X[(t0 + r) * NH + h] = acc[r];
}

// ---------------- sequential recurrence: 64 blocks, weights LDS-resident -----
// Synchronization: per-block flag array (one 128B line per block). Producer
// release pattern: data stores -> s_waitcnt vmcnt(0) (per wave, parallel) ->
// __syncthreads -> tid0 stores flag[b]=t+1. Consumers: ONLY wave 0 polls, lane
// l watching block l's flag (64 parallel single-line polls; lane l==b skips its
// own block). No atomic RMW chain, no gen broadcast, minimal poll traffic.
// After the A-barrier all 1024 threads gather the state vector in ONE parallel
// coalesced uncached load.
__launch_bounds__(RT, 1)
__global__ void recur(const float* __restrict__ Wr1, const float* __restrict__ Wr2,
                      const float* __restrict__ X1,  const float* __restrict__ X2,
                      float* Z12, float* Z2, float* Z1hist, int* flags) {
    __shared__ float lW1[HPB][NHP];        // 64 KB (+pad)
    __shared__ float lW2[HPB][NHP];        // 64 KB (+pad)
    __shared__ float sz [2][NH];           // 8 KB  z12 staging (double-buffered)
    __shared__ float sz2[2][NH];           // 8 KB  z2 staging  (double-buffered)

    const int tid = threadIdx.x;
    const int b   = blockIdx.x;
    const int h0  = b * HPB;

    // one-time weight residency: consecutive tid -> consecutive h (64B chunks)
    for (int idx = tid; idx < HPB * NH; idx += RT) {
        int hw = idx & (HPB - 1);
        int k  = idx >> 4;                 // HPB == 16
        lW1[hw][k] = Wr1[(size_t)k * NH + h0 + hw];
        lW2[hw][k] = Wr2[(size_t)k * NH + h0 + hw];
    }
    __syncthreads();

    const int w = tid >> 6;                // wave 0..15 <-> hidden unit
    const int l = tid & 63;
    const int h = h0 + w;

    float z2h = 0.0f;                      // lane-0-owned z2[h] register state

    for (int t = 0; t < ND; ++t) {
        const bool even = (t & 1) == 0;
        const int  q    = t >> 1;

        // wait until every block has published step-t inputs (skip own flag)
        if (t != 0 && w == 0 && l != b) {
            const int* fp = flags + l * 32;            // one 128B line per block
            while (ALF(fp) < t) { }
        }
        __syncthreads();                   // A: flag confirmation -> safe to load

        // gather step-t state: one parallel coalesced uncached load per thread
        float xv1  = X1[t * NH + h];       // cached broadcast load
        float z12v = ALF(Z12 + (t & 1) * NH + tid);
        float xv2 = 0.0f, z2v = 0.0f;
        if (even) {
            xv2 = X2[t * NH + h];
            z2v = ALF(Z2 + (q & 1) * NH + tid);
        }
        sz[t & 1][tid] = z12v;
        if (even) sz2[q & 1][tid] = z2v;
        __syncthreads();                   // B: LDS staging complete

        float r1 = 0.0f, r2 = 0.0f;
        #pragma unroll
        for (int j = 0; j < 16; ++j) {
            int k = l + 64 * j;            // conflict-free LDS
            r1 += sz[t & 1][k] * lW1[w][k];
        }
        if (even) {
            #pragma unroll
            for (int j = 0; j < 16; ++j) {
                int k = l + 64 * j;
                r2 += sz2[q & 1][k] * lW2[w][k];
            }
        }
        #pragma unroll
        for (int off = 32; off; off >>= 1) r1 += __shfl_xor(r1, off, 64);
        if (even) {
            #pragma unroll
            for (int off = 32; off; off >>= 1) r2 += __shfl_xor(r2, off, 64);
        }

        if (l == 0) {
            float z1n = tanhf(xv1 + r1);
            if (even) z2h = tanhf(xv2 + r2);
            Z1hist[t * NH + h] = z1n;      // plain cached store (read post-kernel)
            ASF(Z12 + ((t + 1) & 1) * NH + h, z1n + z2h);
            if (even) ASF(Z2 + (((q + 1) & 1)) * NH + h, z2h);
        }

        if (t == ND - 1) break;            // nothing to publish after last step

        __builtin_amdgcn_s_waitcnt(0);     // release: own wave's stores at IF
        __syncthreads();                   // C: all 16 waves' stores visible
        if (tid == 0) ASF(flags + b * 32, t + 1);
    }
}

// ---------------- output projection, t-tiled: out[t] = tanh(z1[t]@Wout + b) --
__global__ void outproj(const float* __restrict__ Z1hist,
                        const float* __restrict__ Wout,
                        const float* __restrict__ bout,
                        float* __restrict__ out) {
    const int t0 = blockIdx.x * OTB;
    const int o  = threadIdx.x;

    __shared__ float lz[OTB][NH];          // 32 KB
    for (int idx = threadIdx.x; idx < OTB * NH; idx += 256) {
        int r = idx >> 10, c = idx & (NH - 1);
        lz[r][c] = Z1hist[(t0 + r) * NH + c];
    }
    __syncthreads();

    float acc[OTB];
    float bias = bout[o];
    #pragma unroll
    for (int r = 0; r < OTB; ++r) acc[r] = bias;

    for (int hh = 0; hh < NH; ++hh) {
        float wv = Wout[hh * NO + o];      // coalesced over o
        #pragma unroll
        for (int r = 0; r < OTB; ++r) acc[r] += lz[r][hh] * wv;
    }
    #pragma unroll
    for (int r = 0; r < OTB; ++r) out[(t0 + r) * NO + o] = tanhf(acc[r]);
}

extern "C" void kernel_launch(void* const* d_in, const int* in_sizes, int n_in,
                              void* d_out, int out_size, void* d_ws, size_t ws_size,
                              hipStream_t stream) {
    const float* x     = (const float*)d_in[0];
    const float* Win1  = (const float*)d_in[1];
    const float* b1    = (const float*)d_in[2];
    const float* Wr1   = (const float*)d_in[3];
    const float* Win2  = (const float*)d_in[4];
    const float* b2    = (const float*)d_in[5];
    const float* Wr2   = (const float*)d_in[6];
    const float* Wout  = (const float*)d_in[7];
    const float* bout  = (const float*)d_in[8];
    float* out = (float*)d_out;

    // workspace layout (floats)
    float* ws    = (float*)d_ws;
    float* Z12   = ws;                      // 2*NH   ping-pong z1+z2
    float* Z2    = Z12 + 2 * NH;            // 2*NH   ping-pong z2 (even steps)
    int*   flags = (int*)(Z2 + 2 * NH);     // RB*32 ints (one 128B line/block)
    float* Z1h   = (float*)(flags + RB * 32); // ND*NH
    float* X1    = Z1h + ND * NH;           // ND*NH
    float* X2    = X1 + ND * NH;            // ND*NH

    // zero initial state + flags (ws is re-poisoned before every call)
    hipMemsetAsync(Z12, 0, (4 * NH) * sizeof(float) + RB * 32 * sizeof(int), stream);

    dim3 xg(NH / 256, ND / XTB, 2);
    xproj<<<xg, 256, 0, stream>>>(x, Win1, b1, Win2, b2, X1, X2);

    recur<<<RB, RT, 0, stream>>>(Wr1, Wr2, X1, X2, Z12, Z2, Z1h, flags);

    outproj<<<ND / OTB, NO, 0, stream>>>(Z1h, Wout, bout, out);
}